// Round 15
// baseline (219.106 us; speedup 1.0000x reference)
//
#include <hip/hip_runtime.h>
#include <hip/hip_bf16.h>

namespace {

constexpr int kN  = 1024;
constexpr int kU  = 64;
constexpr int kFP = 80;   // padded feature dim (5 tiles of 16)

typedef __attribute__((ext_vector_type(4))) float f32x4;
typedef __attribute__((ext_vector_type(8))) short sv8;
typedef unsigned int u32;
typedef unsigned short u16;

__device__ __forceinline__ u32 pack_bf2(float a, float b) {
  __hip_bfloat16 ha = __float2bfloat16(a);
  __hip_bfloat16 hb = __float2bfloat16(b);
  u16 ua = *reinterpret_cast<u16*>(&ha);
  u16 ub = *reinterpret_cast<u16*>(&hb);
  return (u32)ua | ((u32)ub << 16);
}

__device__ __forceinline__ u16 bf16bits(float a) {
  __hip_bfloat16 h = __float2bfloat16(a);
  return *reinterpret_cast<u16*>(&h);
}

__device__ __forceinline__ float bflo(u32 v) {
  u32 x = v << 16;
  return *reinterpret_cast<float*>(&x);
}
__device__ __forceinline__ float bfhi(u32 v) {
  u32 x = v & 0xffff0000u;
  return *reinterpret_cast<float*>(&x);
}

__device__ __forceinline__ void gl16(const void* g, void* l) {
  __builtin_amdgcn_global_load_lds(
      (const __attribute__((address_space(1))) u32*)g,
      (__attribute__((address_space(3))) u32*)l, 16, 0, 0);
}

// NT (non-temporal / no-L2-allocate) variant for the read-once A-stream.
__device__ __forceinline__ void gl16nt(const void* g, void* l) {
  __builtin_amdgcn_global_load_lds(
      (const __attribute__((address_space(1))) u32*)g,
      (__attribute__((address_space(3))) u32*)l, 16, 0, 2 /* NT */);
}

// ---------------------------------------------------------------------------
// K0: supports f32 -> TILED bf16, INTERLEAVED chunk order (verbatim R14).
// ---------------------------------------------------------------------------
__global__ __launch_bounds__(256) void convert_sup(
    const f32x4* __restrict__ sup4, u16* __restrict__ supb) {
  const int bx = blockIdx.x;
  const int b  = bx >> 6;
  const int rg = bx & 63;
  const int tile = rg >> 2, w = rg & 3;
  const int t  = threadIdx.x;
  const int l64 = t & 63, tg = t >> 6;
  const int T2 = l64 >> 5, ks = (l64 >> 4) & 1, q = (l64 >> 2) & 3;
  const int e  = (l64 & 3) * 2;

  __shared__ u16 CL[4096];  // 8 KB

  const size_t rowbase = (size_t)(b * 1024 + rg * 16) * 512;  // f32x4 units
  const int region0 = (b * 16 + tile) * 2;

#pragma unroll 1
  for (int jc = 0; jc < 8; ++jc) {
    f32x4 v0 = __builtin_nontemporal_load(sup4 + rowbase + (size_t)(tg) * 512 + jc * 64 + l64);
    f32x4 v1 = __builtin_nontemporal_load(sup4 + rowbase + (size_t)(tg + 4) * 512 + jc * 64 + l64);
    f32x4 v2 = __builtin_nontemporal_load(sup4 + rowbase + (size_t)(tg + 8) * 512 + jc * 64 + l64);
    f32x4 v3 = __builtin_nontemporal_load(sup4 + rowbase + (size_t)(tg + 12) * 512 + jc * 64 + l64);
    const int ob = T2 * 1024 + ks * 512 + q * 8 + e;
    *reinterpret_cast<u32*>(&CL[ob + (tg) * 32])            = pack_bf2(v0[0], v0[2]);
    *reinterpret_cast<u32*>(&CL[2048 + ob + (tg) * 32])     = pack_bf2(v0[1], v0[3]);
    *reinterpret_cast<u32*>(&CL[ob + (tg + 4) * 32])        = pack_bf2(v1[0], v1[2]);
    *reinterpret_cast<u32*>(&CL[2048 + ob + (tg + 4) * 32]) = pack_bf2(v1[1], v1[3]);
    *reinterpret_cast<u32*>(&CL[ob + (tg + 8) * 32])        = pack_bf2(v2[0], v2[2]);
    *reinterpret_cast<u32*>(&CL[2048 + ob + (tg + 8) * 32]) = pack_bf2(v2[1], v2[3]);
    *reinterpret_cast<u32*>(&CL[ob + (tg + 12) * 32])       = pack_bf2(v3[0], v3[2]);
    *reinterpret_cast<u32*>(&CL[2048 + ob + (tg + 12) * 32])= pack_bf2(v3[1], v3[3]);
    __syncthreads();
#pragma unroll
    for (int pi2 = 0; pi2 < 2; ++pi2) {
      int pi = tg + pi2 * 4;             // 0..7 = [s][T2o][kso]
      int so = pi >> 2, T2o = (pi >> 1) & 1, kso = pi & 1;
      uint4 d = *reinterpret_cast<const uint4*>(
          &CL[so * 2048 + T2o * 1024 + kso * 512 + (l64 & 15) * 32 + (l64 >> 4) * 8]);
      int T = jc * 2 + T2o;
      u16* dst = supb + ((size_t)T * 1024 + region0 + so) * 4096 +
                 kso * 2048 + w * 512 + (size_t)l64 * 8;
      *reinterpret_cast<uint4*>(dst) = d;
    }
    __syncthreads();
  }
}

// ---------------------------------------------------------------------------
// K1: build x0^T bf16 (B, 80, 1024).  (verbatim R12)
// ---------------------------------------------------------------------------
__global__ __launch_bounds__(256) void build_x0t(
    const float* __restrict__ inputs, const float* __restrict__ h_prev,
    __hip_bfloat16* __restrict__ x0t, __hip_bfloat16* __restrict__ x0tc) {
  const int bx = blockIdx.x;
  const int b  = bx >> 4;
  const int n0 = (bx & 15) * 64;
  const int t  = threadIdx.x;

  __shared__ float hp[64][65];

  const float* hpg = h_prev + (size_t)b * kN * kU + (size_t)n0 * kU;
#pragma unroll
  for (int r = 0; r < 16; ++r) {
    int idx = t + (r << 8);
    hp[idx >> 6][idx & 63] = hpg[idx];
  }
  __syncthreads();

  {
    int u = t >> 2, g = t & 3;
    __hip_bfloat16* dst = x0t + ((size_t)b * kFP + 2 + u) * kN + n0 + g * 16;
#pragma unroll
    for (int k = 0; k < 16; ++k) dst[k] = __float2bfloat16(hp[g * 16 + k][u]);
  }

  if (t < 128) {
    int d = t & 1, nn = t >> 1;
    float v = inputs[((size_t)b * kN + n0 + nn) * 2 + d];
    __hip_bfloat16 bv = __float2bfloat16(v);
    x0t [((size_t)b * kFP + d) * kN + n0 + nn] = bv;
    x0tc[((size_t)b * kFP + d) * kN + n0 + nn] = bv;
  } else {
    int i2 = t - 128;
    __hip_bfloat16 z = __float2bfloat16(0.0f);
#pragma unroll
    for (int r = 0; r < 7; ++r) {
      int idx = i2 + r * 128;
      int row = 66 + (idx >> 6), nn = idx & 63;
      x0t [((size_t)b * kFP + row) * kN + n0 + nn] = z;
      x0tc[((size_t)b * kFP + row) * kN + n0 + nn] = z;
    }
  }
}

// ---------------------------------------------------------------------------
// K2/K4: graph-diffusion einsum (R14 verbatim; single change: A-loads use
// the NT cache-policy bit so the read-once 128 MB stream does not allocate
// into / thrash the 4 MB per-XCD L2, which the reused X-tiles need).
// ---------------------------------------------------------------------------
__global__ __launch_bounds__(512) void einsum_diff(
    const u16* __restrict__ supb, const __hip_bfloat16* __restrict__ x0t,
    u16* __restrict__ xfeat) {
  const int bx = blockIdx.x;
  const int wk = (bx & 7) * 64 + (bx >> 3);  // XCD-chunked bijective (8*64)
  const int b    = wk >> 4;
  const int tile = wk & 15;
  const int i0   = tile * 64;
  const int t    = threadIdx.x;
  const int lane = t & 63;
  const int ww   = t >> 6;     // 0..7
  const int q    = lane >> 4;
  const int lm   = lane & 15;
  const int s    = ww & 1;
  const int ih   = ww >> 1;    // 0..3

  __shared__ u16 Af[2][2][2][4][64][8];  // [buf][s][ks][ih][lane][8]  32 KB
  __shared__ u16 Xf[2][10][64][8];       // [buf][seg][lane][8]        20 KB

  f32x4 acc[5];
#pragma unroll
  for (int n = 0; n < 5; ++n) acc[n] = (f32x4){0.f, 0.f, 0.f, 0.f};

  // A: interleaved chunks — dense chip-wide window per K-step.
  const int region = (b * 16 + tile) * 2 + s;
  const u16* asrc = supb + (size_t)region * 4096 + ih * 512 + (size_t)lane * 8;
  // X: R9/R12 seg formulas (seg = ks*5+n).
  const u16* xg = reinterpret_cast<const u16*>(x0t) + (size_t)b * kFP * kN;
  const int seg1 = ww;
  const int seg2 = ww + 8;
  const u16* xs1 =
      xg + (size_t)((seg1 % 5) * 16 + lm) * kN + (seg1 / 5) * 32 + q * 8;
  const u16* xs2 = (ww < 2)
      ? xg + (size_t)((seg2 % 5) * 16 + lm) * kN + (seg2 / 5) * 32 + q * 8
      : nullptr;

  auto dma = [&](int nb, int T) {
    gl16nt(asrc + (size_t)T * 4194304,        &Af[nb][s][0][ih][0][0]);
    gl16nt(asrc + (size_t)T * 4194304 + 2048, &Af[nb][s][1][ih][0][0]);
    gl16(xs1 + T * 64, &Xf[nb][seg1][0][0]);
    if (ww < 2) gl16(xs2 + T * 64, &Xf[nb][seg2][0][0]);
  };

  auto compute = [&](int nb) {
#pragma unroll
    for (int ks = 0; ks < 2; ++ks) {
      sv8 a = *reinterpret_cast<const sv8*>(&Af[nb][s][ks][ih][lane][0]);
#pragma unroll
      for (int n = 0; n < 5; ++n) {
        sv8 xb = *reinterpret_cast<const sv8*>(&Xf[nb][ks * 5 + n][lane][0]);
        acc[n] = __builtin_amdgcn_mfma_f32_16x16x32_bf16(a, xb, acc[n], 0, 0, 0);
      }
    }
  };

  // prologue: batch 0 staged & visible
  dma(0, 0);
  asm volatile("s_waitcnt vmcnt(0)" ::: "memory");
  __builtin_amdgcn_s_barrier();
  __builtin_amdgcn_sched_barrier(0);

#pragma unroll 1
  for (int T = 0; T < 16; ++T) {
    if (T + 1 <= 15) {
      dma((T + 1) & 1, T + 1);
      if (ww < 2) { asm volatile("s_waitcnt vmcnt(4)" ::: "memory"); }
      else        { asm volatile("s_waitcnt vmcnt(3)" ::: "memory"); }
    } else {
      asm volatile("s_waitcnt vmcnt(0)" ::: "memory");
    }
    __builtin_amdgcn_s_barrier();        // all waves: batch T landed
    __builtin_amdgcn_sched_barrier(0);
    compute(T & 1);
    __builtin_amdgcn_s_barrier();        // reads done before next overwrite
    __builtin_amdgcn_sched_barrier(0);
  }

  // ---- epilogue: acc -> LDS bf16 [64][136] -> coalesced global ----
  u16* ep = &Af[0][0][0][0][0][0];
#pragma unroll
  for (int n = 0; n < 5; ++n) {
    int f = n * 16 + lm;
    if (f < 66) {
#pragma unroll
      for (int r = 0; r < 4; ++r) {
        int row = ih * 16 + q * 4 + r;
        ep[row * 136 + s * 66 + f] = bf16bits(acc[n][r]);
      }
    }
  }
  __syncthreads();
  const u32* ep32 = reinterpret_cast<const u32*>(ep);  // [64][68]
  u32* og = reinterpret_cast<u32*>(xfeat) + ((size_t)b * kN + i0) * 66;
#pragma unroll 1
  for (int g = t; g < 4224; g += 512) {
    int row = g / 66, c = g - row * 66;
    og[g] = ep32[row * 68 + c];
  }
}

// ---------------------------------------------------------------------------
// K3: r/u gates (xfeat bf16).  (verbatim R12)
// ---------------------------------------------------------------------------
__global__ __launch_bounds__(256) void gates_ru(
    const u16* __restrict__ xfeat, const float* __restrict__ rk,
    const float* __restrict__ rbias, const float* __restrict__ uk,
    const float* __restrict__ ubias, const float* __restrict__ inputs,
    const float* __restrict__ h_prev, float* __restrict__ u_buf,
    __hip_bfloat16* __restrict__ x0tc) {
  const int row0 = blockIdx.x * 32;
  const int b = row0 >> 10, n0 = row0 & 1023;
  const int t = threadIdx.x;
  __shared__ float xm[32][134];
  __shared__ float x0s[32][66];

  {
    const u32* xsrc = reinterpret_cast<const u32*>(xfeat) + (size_t)row0 * 66;
#pragma unroll 1
    for (int g = t; g < 2112; g += 256) {
      int row = g / 66, c = g - row * 66;
      u32 v = xsrc[g];
      xm[row][c * 2]     = bflo(v);
      xm[row][c * 2 + 1] = bfhi(v);
    }
  }
#pragma unroll
  for (int r2 = 0; r2 < 8; ++r2) {
    int idx = t + (r2 << 8);
    int rw = idx >> 6, u = idx & 63;
    x0s[rw][2 + u] = h_prev[(size_t)(row0 + rw) * kU + u];
  }
  if (t < 64) x0s[t >> 1][t & 1] = inputs[(size_t)row0 * 2 + t];
  __syncthreads();

  const int cu = t & 15;
  const int rw = (t >> 4) * 2;
  float ar[2][4] = {{0.f,0.f,0.f,0.f},{0.f,0.f,0.f,0.f}};
  float au[2][4] = {{0.f,0.f,0.f,0.f},{0.f,0.f,0.f,0.f}};

#pragma unroll 4
  for (int f = 0; f < 66; ++f) {  // m = 0
    float4 vr = *reinterpret_cast<const float4*>(rk + (size_t)(f * 3) * kU + cu * 4);
    float4 vu = *reinterpret_cast<const float4*>(uk + (size_t)(f * 3) * kU + cu * 4);
    float a0 = x0s[rw][f], a1 = x0s[rw + 1][f];
    ar[0][0] += a0 * vr.x; ar[0][1] += a0 * vr.y; ar[0][2] += a0 * vr.z; ar[0][3] += a0 * vr.w;
    ar[1][0] += a1 * vr.x; ar[1][1] += a1 * vr.y; ar[1][2] += a1 * vr.z; ar[1][3] += a1 * vr.w;
    au[0][0] += a0 * vu.x; au[0][1] += a0 * vu.y; au[0][2] += a0 * vu.z; au[0][3] += a0 * vu.w;
    au[1][0] += a1 * vu.x; au[1][1] += a1 * vu.y; au[1][2] += a1 * vu.z; au[1][3] += a1 * vu.w;
  }
#pragma unroll
  for (int m = 1; m <= 2; ++m) {
#pragma unroll 4
    for (int f = 0; f < 66; ++f) {
      float4 vr = *reinterpret_cast<const float4*>(rk + (size_t)(f * 3 + m) * kU + cu * 4);
      float4 vu = *reinterpret_cast<const float4*>(uk + (size_t)(f * 3 + m) * kU + cu * 4);
      float a0 = xm[rw][(m - 1) * 66 + f], a1 = xm[rw + 1][(m - 1) * 66 + f];
      ar[0][0] += a0 * vr.x; ar[0][1] += a0 * vr.y; ar[0][2] += a0 * vr.z; ar[0][3] += a0 * vr.w;
      ar[1][0] += a1 * vr.x; ar[1][1] += a1 * vr.y; ar[1][2] += a1 * vr.z; ar[1][3] += a1 * vr.w;
      au[0][0] += a0 * vu.x; au[0][1] += a0 * vu.y; au[0][2] += a0 * vu.z; au[0][3] += a0 * vu.w;
      au[1][0] += a1 * vu.x; au[1][1] += a1 * vu.y; au[1][2] += a1 * vu.z; au[1][3] += a1 * vu.w;
    }
  }

#pragma unroll
  for (int rr = 0; rr < 2; ++rr) {
    int grow = row0 + rw + rr;
    int n = n0 + rw + rr;
#pragma unroll
    for (int j = 0; j < 4; ++j) {
      int u = cu * 4 + j;
      float rv = 1.f / (1.f + __expf(-(ar[rr][j] + rbias[u])));
      float uv = 1.f / (1.f + __expf(-(au[rr][j] + ubias[u])));
      u_buf[(size_t)grow * kU + u] = uv;
      float rh = rv * h_prev[(size_t)grow * kU + u];
      x0tc[((size_t)b * kFP + 2 + u) * kN + n] = __float2bfloat16(rh);
    }
  }
}

// ---------------------------------------------------------------------------
// K5: c gate + GRU update (xfeat bf16).  (verbatim R12)
// ---------------------------------------------------------------------------
__global__ __launch_bounds__(256) void gate_c_final(
    const u16* __restrict__ xfeat, const float* __restrict__ ck,
    const float* __restrict__ cbias, const float* __restrict__ inputs,
    const __hip_bfloat16* __restrict__ x0tc, const float* __restrict__ h_prev,
    const float* __restrict__ u_buf, float* __restrict__ out) {
  const int row0 = blockIdx.x * 32;
  const int b = row0 >> 10, n0 = row0 & 1023;
  const int t = threadIdx.x;
  __shared__ float xm[32][134];
  __shared__ float x0c[32][66];

  {
    const u32* xsrc = reinterpret_cast<const u32*>(xfeat) + (size_t)row0 * 66;
#pragma unroll 1
    for (int g = t; g < 2112; g += 256) {
      int row = g / 66, c = g - row * 66;
      u32 v = xsrc[g];
      xm[row][c * 2]     = bflo(v);
      xm[row][c * 2 + 1] = bfhi(v);
    }
  }
#pragma unroll
  for (int r2 = 0; r2 < 8; ++r2) {
    int idx = t + (r2 << 8);
    int u = idx >> 5, nn = idx & 31;
    x0c[nn][2 + u] =
        __bfloat162float(x0tc[((size_t)b * kFP + 2 + u) * kN + n0 + nn]);
  }
  if (t < 64) x0c[t >> 1][t & 1] = inputs[(size_t)row0 * 2 + t];
  __syncthreads();

  const int cu = t & 15;
  const int rw = (t >> 4) * 2;
  float ac[2][4] = {{0.f,0.f,0.f,0.f},{0.f,0.f,0.f,0.f}};

#pragma unroll 4
  for (int f = 0; f < 66; ++f) {  // m = 0
    float4 vc = *reinterpret_cast<const float4*>(ck + (size_t)(f * 3) * kU + cu * 4);
    float a0 = x0c[rw][f], a1 = x0c[rw + 1][f];
    ac[0][0] += a0 * vc.x; ac[0][1] += a0 * vc.y; ac[0][2] += a0 * vc.z; ac[0][3] += a0 * vc.w;
    ac[1][0] += a1 * vc.x; ac[1][1] += a1 * vc.y; ac[1][2] += a1 * vc.z; ac[1][3] += a1 * vc.w;
  }
#pragma unroll
  for (int m = 1; m <= 2; ++m) {
#pragma unroll 4
    for (int f = 0; f < 66; ++f) {
      float4 vc = *reinterpret_cast<const float4*>(ck + (size_t)(f * 3 + m) * kU + cu * 4);
      float a0 = xm[rw][(m - 1) * 66 + f], a1 = xm[rw + 1][(m - 1) * 66 + f];
      ac[0][0] += a0 * vc.x; ac[0][1] += a0 * vc.y; ac[0][2] += a0 * vc.z; ac[0][3] += a0 * vc.w;
      ac[1][0] += a1 * vc.x; ac[1][1] += a1 * vc.y; ac[1][2] += a1 * vc.z; ac[1][3] += a1 * vc.w;
    }
  }

#pragma unroll
  for (int rr = 0; rr < 2; ++rr) {
    int grow = row0 + rw + rr;
#pragma unroll
    for (int j = 0; j < 4; ++j) {
      int u = cu * 4 + j;
      float cv = tanhf(ac[rr][j] + cbias[u]);
      float uv = u_buf[(size_t)grow * kU + u];
      float hp = h_prev[(size_t)grow * kU + u];
      out[(size_t)grow * kU + u] = uv * hp + (1.f - uv) * cv;
    }
  }
}

}  // namespace

extern "C" void kernel_launch(void* const* d_in, const int* in_sizes, int n_in,
                              void* d_out, int out_size, void* d_ws, size_t ws_size,
                              hipStream_t stream) {
  const float* inputs = (const float*)d_in[0];
  const float* sup    = (const float*)d_in[1];
  const float* h_prev = (const float*)d_in[2];
  const float* rk     = (const float*)d_in[3];
  const float* rbias  = (const float*)d_in[4];
  const float* uk     = (const float*)d_in[5];
  const float* ubias  = (const float*)d_in[6];
  const float* ck     = (const float*)d_in[7];
  const float* cbias  = (const float*)d_in[8];
  float* out = (float*)d_out;

  char* ws = (char*)d_ws;
  __hip_bfloat16* x0t   = (__hip_bfloat16*)(ws);                    //  5,242,880 B
  __hip_bfloat16* x0tc  = (__hip_bfloat16*)(ws + 5242880);          //  5,242,880 B
  u16*            xfeat = (u16*)(ws + 10485760);                    //  8,650,752 B
  float*          u_buf = (float*)(ws + 19136512);                  //  8,388,608 B
  u16*            supb  = (u16*)(ws + 27525120);                    // 134,217,728 B

  hipLaunchKernelGGL(convert_sup, dim3(2048), dim3(256), 0, stream,
                     (const f32x4*)sup, supb);
  hipLaunchKernelGGL(build_x0t, dim3(512), dim3(256), 0, stream,
                     inputs, h_prev, x0t, x0tc);
  hipLaunchKernelGGL(einsum_diff, dim3(512), dim3(512), 0, stream,
                     supb, x0t, xfeat);
  hipLaunchKernelGGL(gates_ru, dim3(1024), dim3(256), 0, stream,
                     xfeat, rk, rbias, uk, ubias, inputs, h_prev, u_buf, x0tc);
  hipLaunchKernelGGL(einsum_diff, dim3(512), dim3(512), 0, stream,
                     supb, x0tc, xfeat);
  hipLaunchKernelGGL(gate_c_final, dim3(1024), dim3(256), 0, stream,
                     xfeat, ck, cbias, inputs, x0tc, h_prev, u_buf, out);
}

// Round 16
// 210.333 us; speedup vs baseline: 1.0417x; 1.0417x over previous
//
#include <hip/hip_runtime.h>
#include <hip/hip_bf16.h>

namespace {

constexpr int kN  = 1024;
constexpr int kU  = 64;
constexpr int kFP = 80;   // padded feature dim (5 tiles of 16)

typedef __attribute__((ext_vector_type(4))) float f32x4;
typedef __attribute__((ext_vector_type(8))) short sv8;
typedef unsigned int u32;
typedef unsigned short u16;

__device__ __forceinline__ u32 pack_bf2(float a, float b) {
  __hip_bfloat16 ha = __float2bfloat16(a);
  __hip_bfloat16 hb = __float2bfloat16(b);
  u16 ua = *reinterpret_cast<u16*>(&ha);
  u16 ub = *reinterpret_cast<u16*>(&hb);
  return (u32)ua | ((u32)ub << 16);
}

__device__ __forceinline__ u16 bf16bits(float a) {
  __hip_bfloat16 h = __float2bfloat16(a);
  return *reinterpret_cast<u16*>(&h);
}

__device__ __forceinline__ float bflo(u32 v) {
  u32 x = v << 16;
  return *reinterpret_cast<float*>(&x);
}
__device__ __forceinline__ float bfhi(u32 v) {
  u32 x = v & 0xffff0000u;
  return *reinterpret_cast<float*>(&x);
}

__device__ __forceinline__ void gl16(const void* g, void* l) {
  __builtin_amdgcn_global_load_lds(
      (const __attribute__((address_space(1))) u32*)g,
      (__attribute__((address_space(3))) u32*)l, 16, 0, 0);
}

// ---------------------------------------------------------------------------
// K0: supports f32 -> bf16 (s-interleaved), pure linear stream.
// ---------------------------------------------------------------------------
__global__ __launch_bounds__(256) void convert_sup(
    const f32x4* __restrict__ sup4, uint2* __restrict__ outb) {
  const size_t n4 = (size_t)16 * 1024 * 1024;  // 64M floats / 4
  size_t idx = (size_t)blockIdx.x * 256 + threadIdx.x;
  const size_t stride = (size_t)gridDim.x * 256;
#pragma unroll 1
  for (; idx < n4; idx += stride) {
    f32x4 v = __builtin_nontemporal_load(sup4 + idx);
    uint2 o;
    o.x = pack_bf2(v[0], v[1]);
    o.y = pack_bf2(v[2], v[3]);
    outb[idx] = o;
  }
}

// ---------------------------------------------------------------------------
// K1: build x0^T bf16 (B, 80, 1024).
// ---------------------------------------------------------------------------
__global__ __launch_bounds__(256) void build_x0t(
    const float* __restrict__ inputs, const float* __restrict__ h_prev,
    __hip_bfloat16* __restrict__ x0t, __hip_bfloat16* __restrict__ x0tc) {
  const int bx = blockIdx.x;
  const int b  = bx >> 4;
  const int n0 = (bx & 15) * 64;
  const int t  = threadIdx.x;

  __shared__ float hp[64][65];

  const float* hpg = h_prev + (size_t)b * kN * kU + (size_t)n0 * kU;
#pragma unroll
  for (int r = 0; r < 16; ++r) {
    int idx = t + (r << 8);
    hp[idx >> 6][idx & 63] = hpg[idx];
  }
  __syncthreads();

  {
    int u = t >> 2, g = t & 3;
    __hip_bfloat16* dst = x0t + ((size_t)b * kFP + 2 + u) * kN + n0 + g * 16;
#pragma unroll
    for (int k = 0; k < 16; ++k) dst[k] = __float2bfloat16(hp[g * 16 + k][u]);
  }

  if (t < 128) {
    int d = t & 1, nn = t >> 1;
    float v = inputs[((size_t)b * kN + n0 + nn) * 2 + d];
    __hip_bfloat16 bv = __float2bfloat16(v);
    x0t [((size_t)b * kFP + d) * kN + n0 + nn] = bv;
    x0tc[((size_t)b * kFP + d) * kN + n0 + nn] = bv;
  } else {
    int i2 = t - 128;
    __hip_bfloat16 z = __float2bfloat16(0.0f);
#pragma unroll
    for (int r = 0; r < 7; ++r) {
      int idx = i2 + r * 128;
      int row = 66 + (idx >> 6), nn = idx & 63;
      x0t [((size_t)b * kFP + row) * kN + n0 + nn] = z;
      x0tc[((size_t)b * kFP + row) * kN + n0 + nn] = z;
    }
  }
}

// ---------------------------------------------------------------------------
// K2/K4: graph-diffusion einsum, bf16 MFMA. Depth-2 prefetch, triple-buffered
// LDS, counted vmcnt mid-loop. RACE-SAFE ordering: compute(T) sits BEFORE the
// end-of-step barrier, so the next step's DMA write to buf T%3 (issued only
// after all waves pass that barrier) cannot collide with compute(T)'s reads.
// ---------------------------------------------------------------------------
__global__ __launch_bounds__(512, 4) void einsum_diff(
    const u32* __restrict__ supb, const __hip_bfloat16* __restrict__ x0t,
    u16* __restrict__ xfeat) {
  const int bx = blockIdx.x;
  const int wk = (bx & 7) * 64 + (bx >> 3);  // XCD-chunked (512 = 8*64)
  const int b  = wk >> 4;
  const int i0 = (wk & 15) << 6;
  const int t    = threadIdx.x;
  const int lane = t & 63;
  const int w    = t >> 6;       // 0..7
  const int q    = lane >> 4;
  const int lm   = lane & 15;
  const int s    = w & 1;
  const int ih   = w >> 1;       // 0..3

  __shared__ u16 Af[3][8192];        // 3 x 16 KB  [s(8K)][ks(4K)][ihh(1K)][slot][8]
  __shared__ u16 Xf[3][10][64][8];   // 3 x 10 KB

  f32x4 acc[5];
#pragma unroll
  for (int n = 0; n < 5; ++n) acc[n] = (f32x4){0.f, 0.f, 0.f, 0.f};

  const u32* sb = supb + ((size_t)b * kN + i0) * kN;
  const u16* xg = reinterpret_cast<const u16*>(x0t) + (size_t)b * kFP * kN;

  // ---- A staging unit: thread -> (row ii, j8-group jb), 32 B contiguous ----
  const int ii = t >> 3, jb = t & 7;
  const u32* aSrc = sb + (size_t)ii * kN + jb * 8;
  const int ksA = jb >> 2, q2 = jb & 3;
  const int ihhA = ii >> 4, lm2 = ii & 15;
  const int aOff = ksA * 4096 + ihhA * 1024 +
                   (((q2 * 16 + lm2) * 16) ^ (q2 << 4) ^ (ksA << 6));
  char* const afBase = (char*)&Af[0][0];

  // ---- X DMA sources (seg = ks*5+n); wave w -> seg w, (w<2) seg w+8 ----
  const int seg1 = w;
  const int seg2 = w + 8;
  const u16* xs1 =
      xg + (size_t)((seg1 % 5) * 16 + lm) * kN + (seg1 / 5) * 32 + q * 8;
  const u16* xs2 = (w < 2)
      ? xg + (size_t)((seg2 % 5) * 16 + lm) * kN + (seg2 / 5) * 32 + q * 8
      : nullptr;

  auto dmaX = [&](int nb, int T) {
    int jo = T * 64;
    gl16(xs1 + jo, &Xf[nb][seg1][0][0]);
    if (w < 2) gl16(xs2 + jo, &Xf[nb][seg2][0][0]);
  };

  uint4 WA[3], WB[3];  // literal-indexed only (SROA to regs)

  auto loadA = [&](uint4& A1, uint4& A2, int T) {
    const u32* p = aSrc + T * 64;
    A1 = *reinterpret_cast<const uint4*>(p);
    A2 = *reinterpret_cast<const uint4*>(p + 4);
  };

  auto packW = [&](const uint4& A1, const uint4& A2, int nb) {
    u32 p0[4], p1[4];
    p0[0] = (A1.x & 0xffffu) | (A1.y << 16);
    p0[1] = (A1.z & 0xffffu) | (A1.w << 16);
    p0[2] = (A2.x & 0xffffu) | (A2.y << 16);
    p0[3] = (A2.z & 0xffffu) | (A2.w << 16);
    p1[0] = (A1.x >> 16) | (A1.y & 0xffff0000u);
    p1[1] = (A1.z >> 16) | (A1.w & 0xffff0000u);
    p1[2] = (A2.x >> 16) | (A2.y & 0xffff0000u);
    p1[3] = (A2.z >> 16) | (A2.w & 0xffff0000u);
    char* base = afBase + nb * 16384 + aOff;
    *reinterpret_cast<uint4*>(base)        = (uint4){p0[0], p0[1], p0[2], p0[3]};
    *reinterpret_cast<uint4*>(base + 8192) = (uint4){p1[0], p1[1], p1[2], p1[3]};
  };

  auto compute = [&](int nb) {
#pragma unroll
    for (int ks = 0; ks < 2; ++ks) {
      const char* ab = afBase + nb * 16384 + s * 8192 + ks * 4096 + ih * 1024;
      sv8 a = *reinterpret_cast<const sv8*>(
          ab + (((q * 16 + lm) * 16) ^ (q << 4) ^ (ks << 6)));
#pragma unroll
      for (int n = 0; n < 5; ++n) {
        sv8 xb = *reinterpret_cast<const sv8*>(&Xf[nb][ks * 5 + n][lane][0]);
        acc[n] = __builtin_amdgcn_mfma_f32_16x16x32_bf16(a, xb, acc[n], 0, 0, 0);
      }
    }
  };

  // ---- prologue: batches 0 and 1 in flight; pack 0; make buf0 visible ----
  dmaX(0, 0); loadA(WA[0], WB[0], 0);
  dmaX(1, 1); loadA(WA[1], WB[1], 1);
  if (w < 2) { asm volatile("s_waitcnt vmcnt(4)" ::: "memory"); }
  else       { asm volatile("s_waitcnt vmcnt(3)" ::: "memory"); }
  packW(WA[0], WB[0], 0);
  asm volatile("s_waitcnt lgkmcnt(0)" ::: "memory");
  __builtin_amdgcn_s_barrier();
  __builtin_amdgcn_sched_barrier(0);

  // STEP(T): issue(T+2); vmcnt -> batch T+1 landed (T+2 in flight);
  //          packW(T+1); lgkm(0); compute(T); barrier.
#define STEP(T)                                                             \
  {                                                                         \
    if ((T) + 2 <= 15) {                                                    \
      dmaX(((T) + 2) % 3, (T) + 2);                                         \
      loadA(WA[((T) + 2) % 3], WB[((T) + 2) % 3], (T) + 2);                 \
      if (w < 2) { asm volatile("s_waitcnt vmcnt(4)" ::: "memory"); }       \
      else       { asm volatile("s_waitcnt vmcnt(3)" ::: "memory"); }       \
    } else if ((T) + 1 <= 15) {                                             \
      asm volatile("s_waitcnt vmcnt(0)" ::: "memory");                      \
    }                                                                       \
    if ((T) + 1 <= 15) {                                                    \
      packW(WA[((T) + 1) % 3], WB[((T) + 1) % 3], ((T) + 1) % 3);           \
      asm volatile("s_waitcnt lgkmcnt(0)" ::: "memory");                    \
    }                                                                       \
    __builtin_amdgcn_sched_barrier(0);                                      \
    compute((T) % 3);                                                       \
    __builtin_amdgcn_s_barrier();                                           \
    __builtin_amdgcn_sched_barrier(0);                                      \
  }

  STEP(0)  STEP(1)  STEP(2)  STEP(3)
  STEP(4)  STEP(5)  STEP(6)  STEP(7)
  STEP(8)  STEP(9)  STEP(10) STEP(11)
  STEP(12) STEP(13) STEP(14) STEP(15)
#undef STEP

  // ---- epilogue: acc -> LDS bf16 [64][136] -> coalesced global ----
  u16* ep = (u16*)afBase;
#pragma unroll
  for (int n = 0; n < 5; ++n) {
    int f = n * 16 + lm;
    if (f < 66) {
#pragma unroll
      for (int r = 0; r < 4; ++r) {
        int row = ih * 16 + q * 4 + r;
        ep[row * 136 + s * 66 + f] = bf16bits(acc[n][r]);
      }
    }
  }
  __syncthreads();
  const u32* ep32 = reinterpret_cast<const u32*>(ep);  // [64][68]
  u32* og = reinterpret_cast<u32*>(xfeat) + ((size_t)b * kN + i0) * 66;
#pragma unroll 1
  for (int g = t; g < 4224; g += 512) {
    int row = g / 66, c = g - row * 66;
    og[g] = ep32[row * 68 + c];
  }
}

// ---------------------------------------------------------------------------
// K3: r/u gates (xfeat bf16).
// ---------------------------------------------------------------------------
__global__ __launch_bounds__(256) void gates_ru(
    const u16* __restrict__ xfeat, const float* __restrict__ rk,
    const float* __restrict__ rbias, const float* __restrict__ uk,
    const float* __restrict__ ubias, const float* __restrict__ inputs,
    const float* __restrict__ h_prev, float* __restrict__ u_buf,
    __hip_bfloat16* __restrict__ x0tc) {
  const int row0 = blockIdx.x * 32;
  const int b = row0 >> 10, n0 = row0 & 1023;
  const int t = threadIdx.x;
  __shared__ float xm[32][134];
  __shared__ float x0s[32][66];

  {
    const u32* xsrc = reinterpret_cast<const u32*>(xfeat) + (size_t)row0 * 66;
#pragma unroll 1
    for (int g = t; g < 2112; g += 256) {
      int row = g / 66, c = g - row * 66;
      u32 v = xsrc[g];
      xm[row][c * 2]     = bflo(v);
      xm[row][c * 2 + 1] = bfhi(v);
    }
  }
#pragma unroll
  for (int r2 = 0; r2 < 8; ++r2) {
    int idx = t + (r2 << 8);
    int rw = idx >> 6, u = idx & 63;
    x0s[rw][2 + u] = h_prev[(size_t)(row0 + rw) * kU + u];
  }
  if (t < 64) x0s[t >> 1][t & 1] = inputs[(size_t)row0 * 2 + t];
  __syncthreads();

  const int cu = t & 15;
  const int rw = (t >> 4) * 2;
  float ar[2][4] = {{0.f,0.f,0.f,0.f},{0.f,0.f,0.f,0.f}};
  float au[2][4] = {{0.f,0.f,0.f,0.f},{0.f,0.f,0.f,0.f}};

#pragma unroll 4
  for (int f = 0; f < 66; ++f) {  // m = 0
    float4 vr = *reinterpret_cast<const float4*>(rk + (size_t)(f * 3) * kU + cu * 4);
    float4 vu = *reinterpret_cast<const float4*>(uk + (size_t)(f * 3) * kU + cu * 4);
    float a0 = x0s[rw][f], a1 = x0s[rw + 1][f];
    ar[0][0] += a0 * vr.x; ar[0][1] += a0 * vr.y; ar[0][2] += a0 * vr.z; ar[0][3] += a0 * vr.w;
    ar[1][0] += a1 * vr.x; ar[1][1] += a1 * vr.y; ar[1][2] += a1 * vr.z; ar[1][3] += a1 * vr.w;
    au[0][0] += a0 * vu.x; au[0][1] += a0 * vu.y; au[0][2] += a0 * vu.z; au[0][3] += a0 * vu.w;
    au[1][0] += a1 * vu.x; au[1][1] += a1 * vu.y; au[1][2] += a1 * vu.z; au[1][3] += a1 * vu.w;
  }
#pragma unroll
  for (int m = 1; m <= 2; ++m) {
#pragma unroll 4
    for (int f = 0; f < 66; ++f) {
      float4 vr = *reinterpret_cast<const float4*>(rk + (size_t)(f * 3 + m) * kU + cu * 4);
      float4 vu = *reinterpret_cast<const float4*>(uk + (size_t)(f * 3 + m) * kU + cu * 4);
      float a0 = xm[rw][(m - 1) * 66 + f], a1 = xm[rw + 1][(m - 1) * 66 + f];
      ar[0][0] += a0 * vr.x; ar[0][1] += a0 * vr.y; ar[0][2] += a0 * vr.z; ar[0][3] += a0 * vr.w;
      ar[1][0] += a1 * vr.x; ar[1][1] += a1 * vr.y; ar[1][2] += a1 * vr.z; ar[1][3] += a1 * vr.w;
      au[0][0] += a0 * vu.x; au[0][1] += a0 * vu.y; au[0][2] += a0 * vu.z; au[0][3] += a0 * vu.w;
      au[1][0] += a1 * vu.x; au[1][1] += a1 * vu.y; au[1][2] += a1 * vu.z; au[1][3] += a1 * vu.w;
    }
  }

#pragma unroll
  for (int rr = 0; rr < 2; ++rr) {
    int grow = row0 + rw + rr;
    int n = n0 + rw + rr;
#pragma unroll
    for (int j = 0; j < 4; ++j) {
      int u = cu * 4 + j;
      float rv = 1.f / (1.f + __expf(-(ar[rr][j] + rbias[u])));
      float uv = 1.f / (1.f + __expf(-(au[rr][j] + ubias[u])));
      u_buf[(size_t)grow * kU + u] = uv;
      float rh = rv * h_prev[(size_t)grow * kU + u];
      x0tc[((size_t)b * kFP + 2 + u) * kN + n] = __float2bfloat16(rh);
    }
  }
}

// ---------------------------------------------------------------------------
// K5: c gate + GRU update (xfeat bf16).
// ---------------------------------------------------------------------------
__global__ __launch_bounds__(256) void gate_c_final(
    const u16* __restrict__ xfeat, const float* __restrict__ ck,
    const float* __restrict__ cbias, const float* __restrict__ inputs,
    const __hip_bfloat16* __restrict__ x0tc, const float* __restrict__ h_prev,
    const float* __restrict__ u_buf, float* __restrict__ out) {
  const int row0 = blockIdx.x * 32;
  const int b = row0 >> 10, n0 = row0 & 1023;
  const int t = threadIdx.x;
  __shared__ float xm[32][134];
  __shared__ float x0c[32][66];

  {
    const u32* xsrc = reinterpret_cast<const u32*>(xfeat) + (size_t)row0 * 66;
#pragma unroll 1
    for (int g = t; g < 2112; g += 256) {
      int row = g / 66, c = g - row * 66;
      u32 v = xsrc[g];
      xm[row][c * 2]     = bflo(v);
      xm[row][c * 2 + 1] = bfhi(v);
    }
  }
#pragma unroll
  for (int r2 = 0; r2 < 8; ++r2) {
    int idx = t + (r2 << 8);
    int u = idx >> 5, nn = idx & 31;
    x0c[nn][2 + u] =
        __bfloat162float(x0tc[((size_t)b * kFP + 2 + u) * kN + n0 + nn]);
  }
  if (t < 64) x0c[t >> 1][t & 1] = inputs[(size_t)row0 * 2 + t];
  __syncthreads();

  const int cu = t & 15;
  const int rw = (t >> 4) * 2;
  float ac[2][4] = {{0.f,0.f,0.f,0.f},{0.f,0.f,0.f,0.f}};

#pragma unroll 4
  for (int f = 0; f < 66; ++f) {  // m = 0
    float4 vc = *reinterpret_cast<const float4*>(ck + (size_t)(f * 3) * kU + cu * 4);
    float a0 = x0c[rw][f], a1 = x0c[rw + 1][f];
    ac[0][0] += a0 * vc.x; ac[0][1] += a0 * vc.y; ac[0][2] += a0 * vc.z; ac[0][3] += a0 * vc.w;
    ac[1][0] += a1 * vc.x; ac[1][1] += a1 * vc.y; ac[1][2] += a1 * vc.z; ac[1][3] += a1 * vc.w;
  }
#pragma unroll
  for (int m = 1; m <= 2; ++m) {
#pragma unroll 4
    for (int f = 0; f < 66; ++f) {
      float4 vc = *reinterpret_cast<const float4*>(ck + (size_t)(f * 3 + m) * kU + cu * 4);
      float a0 = xm[rw][(m - 1) * 66 + f], a1 = xm[rw + 1][(m - 1) * 66 + f];
      ac[0][0] += a0 * vc.x; ac[0][1] += a0 * vc.y; ac[0][2] += a0 * vc.z; ac[0][3] += a0 * vc.w;
      ac[1][0] += a1 * vc.x; ac[1][1] += a1 * vc.y; ac[1][2] += a1 * vc.z; ac[1][3] += a1 * vc.w;
    }
  }

#pragma unroll
  for (int rr = 0; rr < 2; ++rr) {
    int grow = row0 + rw + rr;
#pragma unroll
    for (int j = 0; j < 4; ++j) {
      int u = cu * 4 + j;
      float cv = tanhf(ac[rr][j] + cbias[u]);
      float uv = u_buf[(size_t)grow * kU + u];
      float hp = h_prev[(size_t)grow * kU + u];
      out[(size_t)grow * kU + u] = uv * hp + (1.f - uv) * cv;
    }
  }
}

}  // namespace

extern "C" void kernel_launch(void* const* d_in, const int* in_sizes, int n_in,
                              void* d_out, int out_size, void* d_ws, size_t ws_size,
                              hipStream_t stream) {
  const float* inputs = (const float*)d_in[0];
  const float* sup    = (const float*)d_in[1];
  const float* h_prev = (const float*)d_in[2];
  const float* rk     = (const float*)d_in[3];
  const float* rbias  = (const float*)d_in[4];
  const float* uk     = (const float*)d_in[5];
  const float* ubias  = (const float*)d_in[6];
  const float* ck     = (const float*)d_in[7];
  const float* cbias  = (const float*)d_in[8];
  float* out = (float*)d_out;

  char* ws = (char*)d_ws;
  __hip_bfloat16* x0t   = (__hip_bfloat16*)(ws);                    //  5,242,880 B
  __hip_bfloat16* x0tc  = (__hip_bfloat16*)(ws + 5242880);          //  5,242,880 B
  u16*            xfeat = (u16*)(ws + 10485760);                    //  8,650,752 B
  float*          u_buf = (float*)(ws + 19136512);                  //  8,388,608 B
  u32*            supb  = (u32*)(ws + 27525120);                    // 134,217,728 B

  hipLaunchKernelGGL(convert_sup, dim3(4096), dim3(256), 0, stream,
                     (const f32x4*)sup, (uint2*)supb);
  hipLaunchKernelGGL(build_x0t, dim3(512), dim3(256), 0, stream,
                     inputs, h_prev, x0t, x0tc);
  hipLaunchKernelGGL(einsum_diff, dim3(512), dim3(512), 0, stream,
                     supb, x0t, xfeat);
  hipLaunchKernelGGL(gates_ru, dim3(1024), dim3(256), 0, stream,
                     xfeat, rk, rbias, uk, ubias, inputs, h_prev, u_buf, x0tc);
  hipLaunchKernelGGL(einsum_diff, dim3(512), dim3(512), 0, stream,
                     supb, x0tc, xfeat);
  hipLaunchKernelGGL(gate_c_final, dim3(1024), dim3(256), 0, stream,
                     xfeat, ck, cbias, inputs, x0tc, h_prev, u_buf, out);
}